// Round 8
// baseline (287.904 us; speedup 1.0000x reference)
//
#include <hip/hip_runtime.h>
#include <math.h>

#define BB 4
#define TT 1024
#define CCH 1024
#define HH 16
#define DD 64
#define EE 8
#define HID 128
#define CAP 8192    // entries per (proj,pair) list; mean is 65536/28 ~= 2340
#define CH 3        // chunk-blocks per (proj,pair) list

typedef unsigned short u16;
typedef short bf16x8 __attribute__((ext_vector_type(8)));
typedef float f32x4 __attribute__((ext_vector_type(4)));

__device__ __forceinline__ u16 f2bf(float f) {
    unsigned int u = __float_as_uint(f);
    unsigned int r = (u + 0x7FFFu + ((u >> 16) & 1u)) >> 16;   // RNE
    return (u16)r;
}

// ============================================================================
// Kernel 1: router. One thread per token-head g = (b*T+t)*16+h; fp32-exact
// top-2 of 8. Tokens binned by (proj, expert-PAIR): pe = p*64 + lo*8 + hi.
// ============================================================================
__global__ __launch_bounds__(256) void router_kernel(
    const float* __restrict__ x,
    const float* __restrict__ rq, const float* __restrict__ rk, const float* __restrict__ rv,
    unsigned int* __restrict__ counts,
    unsigned int* __restrict__ idxbuf, float2* __restrict__ wtbuf)
{
    const int tid = threadIdx.x;
    const unsigned int g = blockIdx.x * 256 + tid;

    __shared__ float rS[3][64][8];
    __shared__ int lcnt[192];
    __shared__ int lbase[192];

    for (int i = tid; i < 1536; i += 256) {
        int p = i >> 9, rem = i & 511;
        const float* rp = (p == 0) ? rq : (p == 1) ? rk : rv;
        rS[p][rem >> 3][rem & 7] = rp[rem];
    }
    if (tid < 192) lcnt[tid] = 0;
    __syncthreads();

    float lg[3][8];
    #pragma unroll
    for (int p = 0; p < 3; ++p)
        #pragma unroll
        for (int e = 0; e < 8; ++e) lg[p][e] = 0.f;

    const float* xr = x + (size_t)g * 64;
    for (int i4 = 0; i4 < 16; ++i4) {
        float4 xv = ((const float4*)xr)[i4];
        float xa[4] = {xv.x, xv.y, xv.z, xv.w};
        #pragma unroll
        for (int m = 0; m < 4; ++m) {
            int d = i4 * 4 + m;
            #pragma unroll
            for (int p = 0; p < 3; ++p) {
                float4 r0 = *(const float4*)&rS[p][d][0];
                float4 r1 = *(const float4*)&rS[p][d][4];
                lg[p][0] += xa[m] * r0.x; lg[p][1] += xa[m] * r0.y;
                lg[p][2] += xa[m] * r0.z; lg[p][3] += xa[m] * r0.w;
                lg[p][4] += xa[m] * r1.x; lg[p][5] += xa[m] * r1.y;
                lg[p][6] += xa[m] * r1.z; lg[p][7] += xa[m] * r1.w;
            }
        }
    }

    int ppe[3]; float2 pw[3]; int slot[3];
    #pragma unroll
    for (int p = 0; p < 3; ++p) {
        int i1 = 0; float v1 = lg[p][0];
        #pragma unroll
        for (int e = 1; e < 8; ++e) { if (lg[p][e] > v1) { v1 = lg[p][e]; i1 = e; } }
        int i2 = -1; float v2 = -3.402823466e38f;
        #pragma unroll
        for (int e = 0; e < 8; ++e) { if (e != i1 && lg[p][e] > v2) { v2 = lg[p][e]; i2 = e; } }
        float z = __expf(v2 - v1);
        float inv = 1.f / (1.f + z);
        float wa = inv, wb = z * inv;
        int lo = min(i1, i2), hi = max(i1, i2);
        float wlo = (i1 < i2) ? wa : wb;
        float whi = (i1 < i2) ? wb : wa;
        int pel = p * 64 + lo * 8 + hi;
        ppe[p] = pel; pw[p] = make_float2(wlo, whi);
        slot[p] = atomicAdd(&lcnt[pel], 1);
    }
    __syncthreads();
    if (tid < 192) {
        int c = lcnt[tid];
        lbase[tid] = c ? (int)atomicAdd(&counts[tid], (unsigned int)c) : 0;
    }
    __syncthreads();
    #pragma unroll
    for (int p = 0; p < 3; ++p) {
        int pos = lbase[ppe[p]] + slot[p];
        if (pos < CAP) {
            idxbuf[ppe[p] * CAP + pos] = g;
            wtbuf[ppe[p] * CAP + pos]  = pw[p];
        }
    }
}

// ============================================================================
// Kernel 2: pair-grouped expert MLP, bf16 MFMA, wave-independent.
// Block = one of 84 (proj,pair) x CH chunks, 768 threads = 12 waves.
// 32-TOKEN subtiles per wave (2 MFMA M-tiles): halves the serial-chain count
// per wave and halves B-operand LDS reads per token vs the R7 16-token
// version. Numerics per token identical to R7 (passing).
// ============================================================================
__global__ __launch_bounds__(768) void expert_kernel(
    const float* __restrict__ x, const int* __restrict__ pos_ids,
    const float* __restrict__ cosb, const float* __restrict__ sinb,
    const float* __restrict__ w1q, const float* __restrict__ w2q,
    const float* __restrict__ w1k, const float* __restrict__ w2k,
    const float* __restrict__ w1v, const float* __restrict__ w2v,
    const unsigned int* __restrict__ counts,
    const unsigned int* __restrict__ idxbuf, const float2* __restrict__ wtbuf,
    u16* __restrict__ qb, u16* __restrict__ kb, u16* __restrict__ vb)
{
    const int tid = threadIdx.x;
    const int pe84 = blockIdx.x / CH, chunk = blockIdx.x - pe84 * CH;
    const int p = pe84 / 28;
    int q28 = pe84 - p * 28;
    int lo = 0;
    while (q28 >= 7 - lo) { q28 -= 7 - lo; ++lo; }
    const int hi = lo + 1 + q28;
    const int pe = p * 64 + lo * 8 + hi;

    int n = (int)counts[pe]; if (n == 0) return; if (n > CAP) n = CAP;

    const float* w1base = (p == 0) ? w1q : (p == 1) ? w1k : w1v;
    const float* w2base = (p == 0) ? w2q : (p == 1) ? w2k : w2v;
    u16* outp = (p == 0) ? qb : (p == 1) ? kb : vb;
    const unsigned int* il = idxbuf + pe * CAP;
    const float2* wl = wtbuf + pe * CAP;

    __shared__ u16 w1t[2][128][72];    // [e][f][d]  B-operand GEMM1   36.9 KB
    __shared__ u16 w2t[2][64][136];    // [e][g][f]  B-operand GEMM2   34.8 KB
    __shared__ u16 hsw[12][32][40];    // per-wave gelu scratch        30.7 KB

    // ---- stage both experts' weights, bf16-transposed (once) ----
    #pragma unroll
    for (int e = 0; e < 2; ++e) {
        int ex = e ? hi : lo;
        const float* w1 = w1base + ex * 64 * 128;   // [d][f]
        const float* w2 = w2base + ex * 128 * 64;   // [f][g]
        for (int i = tid; i < 8192; i += 768)
            w1t[e][i & 127][i >> 7] = f2bf(w1[i]);
        for (int i = tid; i < 8192; i += 768)
            w2t[e][i & 63][i >> 6] = f2bf(w2[i]);
    }
    __syncthreads();

    const int lane = tid & 63, w = tid >> 6, quad = lane >> 4, m16 = lane & 15;
    const int wid = chunk * 12 + w;
    const int WRK = CH * 12;
    const int nsub = (n + 31) >> 5;

    for (int s = wid; s < nsub; s += WRK) {
        const int base = s * 32;
        // ---- lanes 0..31: per-token metadata; broadcast via shfl ----
        unsigned int gtok = 0, obase = 0; float wlo_ = 0.f, whi_ = 0.f;
        int posv = 0, valid = 0;
        if (lane < 32) {
            int j = base + lane;
            valid = (j < n);
            int jc = valid ? j : (n - 1);
            gtok = il[jc];
            float2 wv = wl[jc];
            wlo_ = valid ? wv.x : 0.f; whi_ = valid ? wv.y : 0.f;
            unsigned int b_ = gtok >> 14, h_ = gtok & 15, t_ = (gtok >> 4) & 1023;
            obase = ((b_ * 16 + h_) * 1024 + t_) * 64;
            posv = pos_ids[b_ * 1024 + t_];
        }

        // ---- A-frags for both 16-token M-tiles ----
        bf16x8 Afr[2][2];
        #pragma unroll
        for (int mt2 = 0; mt2 < 2; ++mt2) {
            unsigned int gm = (unsigned int)__shfl((int)gtok, mt2 * 16 + m16, 64);
            const float* xr = x + (size_t)gm * 64 + 8 * quad;
            float4 xa0 = *(const float4*)(xr);
            float4 xa1 = *(const float4*)(xr + 4);
            float4 xb0 = *(const float4*)(xr + 32);
            float4 xb1 = *(const float4*)(xr + 36);
            bf16x8 A0, A1;
            A0[0] = (short)f2bf(xa0.x); A0[1] = (short)f2bf(xa0.y);
            A0[2] = (short)f2bf(xa0.z); A0[3] = (short)f2bf(xa0.w);
            A0[4] = (short)f2bf(xa1.x); A0[5] = (short)f2bf(xa1.y);
            A0[6] = (short)f2bf(xa1.z); A0[7] = (short)f2bf(xa1.w);
            A1[0] = (short)f2bf(xb0.x); A1[1] = (short)f2bf(xb0.y);
            A1[2] = (short)f2bf(xb0.z); A1[3] = (short)f2bf(xb0.w);
            A1[4] = (short)f2bf(xb1.x); A1[5] = (short)f2bf(xb1.y);
            A1[6] = (short)f2bf(xb1.z); A1[7] = (short)f2bf(xb1.w);
            Afr[mt2][0] = A0; Afr[mt2][1] = A1;
        }

        f32x4 acc2[2][2][4];   // [e][Mtile][nt]
        #pragma unroll
        for (int e = 0; e < 2; ++e)
            #pragma unroll
            for (int mt2 = 0; mt2 < 2; ++mt2)
                #pragma unroll
                for (int nt = 0; nt < 4; ++nt) acc2[e][mt2][nt] = (f32x4){0.f, 0.f, 0.f, 0.f};

        #pragma unroll
        for (int e = 0; e < 2; ++e) {
            #pragma unroll
            for (int kk = 0; kk < 4; ++kk) {
                // --- GEMM1 for 32 hidden features (n-tiles 2kk, 2kk+1), both M ---
                int nt0 = 2 * kk, nt1 = 2 * kk + 1;
                bf16x8 b0a = *(const bf16x8*)&w1t[e][16 * nt0 + m16][8 * quad];
                bf16x8 b0b = *(const bf16x8*)&w1t[e][16 * nt0 + m16][32 + 8 * quad];
                bf16x8 b1a = *(const bf16x8*)&w1t[e][16 * nt1 + m16][8 * quad];
                bf16x8 b1b = *(const bf16x8*)&w1t[e][16 * nt1 + m16][32 + 8 * quad];
                #pragma unroll
                for (int mt2 = 0; mt2 < 2; ++mt2) {
                    f32x4 c0 = (f32x4){0.f, 0.f, 0.f, 0.f};
                    f32x4 c1 = (f32x4){0.f, 0.f, 0.f, 0.f};
                    c0 = __builtin_amdgcn_mfma_f32_16x16x32_bf16(Afr[mt2][0], b0a, c0, 0, 0, 0);
                    c0 = __builtin_amdgcn_mfma_f32_16x16x32_bf16(Afr[mt2][1], b0b, c0, 0, 0, 0);
                    c1 = __builtin_amdgcn_mfma_f32_16x16x32_bf16(Afr[mt2][0], b1a, c1, 0, 0, 0);
                    c1 = __builtin_amdgcn_mfma_f32_16x16x32_bf16(Afr[mt2][1], b1b, c1, 0, 0, 0);
                    #pragma unroll
                    for (int r = 0; r < 4; ++r) {
                        float z = c0[r];
                        float u = 1.5957691216057308f * (z + 0.044715f * z * z * z);
                        hsw[w][mt2 * 16 + 4 * quad + r][m16] = f2bf(z / (1.f + __expf(-u)));
                        float z2 = c1[r];
                        float u2 = 1.5957691216057308f * (z2 + 0.044715f * z2 * z2 * z2);
                        hsw[w][mt2 * 16 + 4 * quad + r][16 + m16] = f2bf(z2 / (1.f + __expf(-u2)));
                    }
                }
                // --- GEMM2 partial: B-frag loaded once, used by both M-tiles ---
                bf16x8 A2_0 = *(const bf16x8*)&hsw[w][m16][8 * quad];
                bf16x8 A2_1 = *(const bf16x8*)&hsw[w][16 + m16][8 * quad];
                #pragma unroll
                for (int nt2 = 0; nt2 < 4; ++nt2) {
                    bf16x8 b2 = *(const bf16x8*)&w2t[e][16 * nt2 + m16][32 * kk + 8 * quad];
                    acc2[e][0][nt2] = __builtin_amdgcn_mfma_f32_16x16x32_bf16(A2_0, b2, acc2[e][0][nt2], 0, 0, 0);
                    acc2[e][1][nt2] = __builtin_amdgcn_mfma_f32_16x16x32_bf16(A2_1, b2, acc2[e][1][nt2], 0, 0, 0);
                }
            }
        }

        // ---- combine experts + RoPE + store (token = mt2*16 + 4*quad + r) ----
        #pragma unroll
        for (int mt2 = 0; mt2 < 2; ++mt2) {
            #pragma unroll
            for (int r = 0; r < 4; ++r) {
                int tk = mt2 * 16 + 4 * quad + r;
                float wlo_r = __shfl(wlo_, tk, 64);
                float whi_r = __shfl(whi_, tk, 64);
                int   pos_r = __shfl(posv, tk, 64);
                unsigned int ob = (unsigned int)__shfl((int)obase, tk, 64);
                int   val_r = __shfl(valid, tk, 64);
                if (p < 2) {
                    #pragma unroll
                    for (int ntp = 0; ntp < 2; ++ntp) {
                        int d = 16 * ntp + m16;
                        float v1 = wlo_r * acc2[0][mt2][ntp][r]     + whi_r * acc2[1][mt2][ntp][r];
                        float v2 = wlo_r * acc2[0][mt2][ntp + 2][r] + whi_r * acc2[1][mt2][ntp + 2][r];
                        float cd = cosb[pos_r * 64 + d];
                        float sd = sinb[pos_r * 64 + d];
                        if (val_r) {
                            outp[ob + d]      = f2bf(v1 * cd - v2 * sd);
                            outp[ob + d + 32] = f2bf(v2 * cd + v1 * sd);
                        }
                    }
                } else {
                    #pragma unroll
                    for (int nt = 0; nt < 4; ++nt) {
                        float v = wlo_r * acc2[0][mt2][nt][r] + whi_r * acc2[1][mt2][nt][r];
                        if (val_r) outp[ob + 16 * nt + m16] = f2bf(v);
                    }
                }
            }
        }
    }
}

// ============================================================================
// Kernel 3: fp32 -> bf16 convert (for o_w)
// ============================================================================
__global__ __launch_bounds__(256) void cvt_bf16_kernel(
    const float* __restrict__ in, u16* __restrict__ out, int n4)
{
    int i = blockIdx.x * 256 + threadIdx.x;
    if (i >= n4) return;
    float4 v = ((const float4*)in)[i];
    unsigned int lov = (unsigned int)f2bf(v.x) | ((unsigned int)f2bf(v.y) << 16);
    unsigned int hiv = (unsigned int)f2bf(v.z) | ((unsigned int)f2bf(v.w) << 16);
    ((uint2*)out)[i] = make_uint2(lov, hiv);
}

// ============================================================================
// Kernel 4: flash attention, bf16 MFMA, R7 numerics (running-max softmax,
// scale in-attn). One q-tile per block, grid 1024 plane-major (qt fastest
// so same-plane blocks cluster for L2 K/V reuse) -> 4 blocks/CU.
// ============================================================================
__global__ __launch_bounds__(256, 4) void attn_kernel(
    const u16* __restrict__ qbp, const u16* __restrict__ kbp,
    const u16* __restrict__ vbp, u16* __restrict__ ao)
{
    const int tid = threadIdx.x;
    const int qt = blockIdx.x & 15;
    const int plane_i = blockIdx.x >> 4;           // 64 planes
    const int h = plane_i & 15, b = plane_i >> 4;
    const size_t plane = (size_t)plane_i * 1024 * 64;
    const u16* qp = qbp + plane;
    const u16* kp = kbp + plane;
    const u16* vp = vbp + plane;

    const int w = tid >> 6, lane = tid & 63, quad = lane >> 4, m16 = lane & 15;
    const int q0 = qt * 64;

    __shared__ u16 Ks[64][72];
    __shared__ u16 Vt[64][72];        // [d][kj]
    __shared__ u16 Ps[4][16][72];     // per-wave P scratch

    // Q A-frags straight from global (row 16w+m16, k = 8*quad [+32])
    const u16* qrow = &qp[(size_t)(q0 + 16 * w + m16) * 64 + 8 * quad];
    bf16x8 aq0 = *(const bf16x8*)(qrow);
    bf16x8 aq1 = *(const bf16x8*)(qrow + 32);

    float m_r[4], l_r[4];
    #pragma unroll
    for (int i = 0; i < 4; ++i) { m_r[i] = -1e30f; l_r[i] = 0.f; }
    f32x4 oacc[4];
    #pragma unroll
    for (int i = 0; i < 4; ++i) oacc[i] = (f32x4){0.f, 0.f, 0.f, 0.f};

    for (int kt = 0; kt <= qt; ++kt) {
        const int k0 = kt * 64;
        __syncthreads();
        {
            int row = tid >> 2, seg = tid & 3;
            const uint4* src = (const uint4*)&kp[(size_t)(k0 + row) * 64 + seg * 16];
            uint4 v0 = src[0], v1 = src[1];
            uint4* dst = (uint4*)&Ks[row][seg * 16];
            dst[0] = v0; dst[1] = v1;
        }
        {
            int kj = tid & 63, dg = tid >> 6;
            #pragma unroll
            for (int pp = 0; pp < 4; ++pp) {
                int d0 = dg * 4 + pp * 16;
                ushort4 v = *(const ushort4*)&vp[(size_t)(k0 + kj) * 64 + d0];
                Vt[d0 + 0][kj] = v.x; Vt[d0 + 1][kj] = v.y;
                Vt[d0 + 2][kj] = v.z; Vt[d0 + 3][kj] = v.w;
            }
        }
        __syncthreads();

        // S = Q K^T
        f32x4 sv[4];
        #pragma unroll
        for (int ct = 0; ct < 4; ++ct) {
            bf16x8 bk0 = *(const bf16x8*)&Ks[16 * ct + m16][8 * quad];
            bf16x8 bk1 = *(const bf16x8*)&Ks[16 * ct + m16][32 + 8 * quad];
            f32x4 acc = (f32x4){0.f, 0.f, 0.f, 0.f};
            acc = __builtin_amdgcn_mfma_f32_16x16x32_bf16(aq0, bk0, acc, 0, 0, 0);
            acc = __builtin_amdgcn_mfma_f32_16x16x32_bf16(aq1, bk1, acc, 0, 0, 0);
            sv[ct] = acc;
        }

        // scale + causal mask (C layout: row = 4*quad+reg, col = 16*ct+m16)
        float s[4][4];
        const bool diag = (kt == qt);
        #pragma unroll
        for (int ct = 0; ct < 4; ++ct)
            #pragma unroll
            for (int reg = 0; reg < 4; ++reg) {
                float v = sv[ct][reg] * 0.125f;
                if (diag) {
                    int col = 16 * ct + m16;
                    int row = 16 * w + 4 * quad + reg;
                    if (col > row) v = -1e30f;
                }
                s[ct][reg] = v;
            }

        // online softmax: running max + rescale
        float nm[4], al[4];
        #pragma unroll
        for (int reg = 0; reg < 4; ++reg) {
            float rm = fmaxf(fmaxf(s[0][reg], s[1][reg]), fmaxf(s[2][reg], s[3][reg]));
            #pragma unroll
            for (int off = 1; off < 16; off <<= 1) rm = fmaxf(rm, __shfl_xor(rm, off, 16));
            float mn = fmaxf(m_r[reg], rm);
            nm[reg] = mn;
            al[reg] = __expf(m_r[reg] - mn);
        }
        #pragma unroll
        for (int reg = 0; reg < 4; ++reg) {
            float sum = 0.f;
            #pragma unroll
            for (int ct = 0; ct < 4; ++ct) {
                float pv = __expf(s[ct][reg] - nm[reg]);
                s[ct][reg] = pv;
                sum += pv;
            }
            #pragma unroll
            for (int off = 1; off < 16; off <<= 1) sum += __shfl_xor(sum, off, 16);
            l_r[reg] = l_r[reg] * al[reg] + sum;
            m_r[reg] = nm[reg];
        }

        // P: C-layout -> A-layout via per-wave LDS (in-wave ordering)
        #pragma unroll
        for (int ct = 0; ct < 4; ++ct)
            #pragma unroll
            for (int reg = 0; reg < 4; ++reg)
                Ps[w][4 * quad + reg][16 * ct + m16] = f2bf(s[ct][reg]);

        #pragma unroll
        for (int dt = 0; dt < 4; ++dt)
            #pragma unroll
            for (int reg = 0; reg < 4; ++reg) oacc[dt][reg] *= al[reg];

        bf16x8 ap0 = *(const bf16x8*)&Ps[w][m16][8 * quad];
        bf16x8 ap1 = *(const bf16x8*)&Ps[w][m16][32 + 8 * quad];
        #pragma unroll
        for (int dt = 0; dt < 4; ++dt) {
            bf16x8 bv0 = *(const bf16x8*)&Vt[16 * dt + m16][8 * quad];
            bf16x8 bv1 = *(const bf16x8*)&Vt[16 * dt + m16][32 + 8 * quad];
            oacc[dt] = __builtin_amdgcn_mfma_f32_16x16x32_bf16(ap0, bv0, oacc[dt], 0, 0, 0);
            oacc[dt] = __builtin_amdgcn_mfma_f32_16x16x32_bf16(ap1, bv1, oacc[dt], 0, 0, 0);
        }
    }

    #pragma unroll
    for (int reg = 0; reg < 4; ++reg) {
        float linv = 1.f / l_r[reg];
        int row = q0 + 16 * w + 4 * quad + reg;
        size_t base = ((size_t)(b * 1024) + row) * 1024 + h * 64;
        #pragma unroll
        for (int dt = 0; dt < 4; ++dt)
            ao[base + 16 * dt + m16] = f2bf(oacc[dt][reg] * linv);
    }
}

// ============================================================================
// Kernel 5: output projection, bf16 MFMA gemm_bt. 128x128 tile, BK=32
// (R4-verbatim, known good).
// ============================================================================
__global__ __launch_bounds__(256) void oproj_kernel(
    const u16* __restrict__ A, const u16* __restrict__ Bw,
    float* __restrict__ out)
{
    const int tid = threadIdx.x;
    const int bn = blockIdx.x & 7;
    const int bm = blockIdx.x >> 3;
    const int m0 = bm * 128, n0 = bn * 128;
    const int w = tid >> 6, lane = tid & 63, quad = lane >> 4, m16 = lane & 15;
    const int wm = (w >> 1) * 64, wn = (w & 1) * 64;

    __shared__ u16 As[128][32];
    __shared__ u16 Bs[128][32];

    f32x4 acc[4][4];
    #pragma unroll
    for (int mt = 0; mt < 4; ++mt)
        #pragma unroll
        for (int nt = 0; nt < 4; ++nt) acc[mt][nt] = (f32x4){0.f, 0.f, 0.f, 0.f};

    for (int k0 = 0; k0 < 1024; k0 += 32) {
        __syncthreads();
        {
            int row = tid >> 1, sg = (tid & 1) * 16;
            const uint4* srcA = (const uint4*)&A[(size_t)(m0 + row) * 1024 + k0 + sg];
            uint4 a0 = srcA[0], a1 = srcA[1];
            uint4* dstA = (uint4*)&As[row][sg];
            dstA[0] = a0; dstA[1] = a1;
            const uint4* srcB = (const uint4*)&Bw[(size_t)(n0 + row) * 1024 + k0 + sg];
            uint4 b0 = srcB[0], b1 = srcB[1];
            uint4* dstB = (uint4*)&Bs[row][sg];
            dstB[0] = b0; dstB[1] = b1;
        }
        __syncthreads();
        bf16x8 af[4], bf_[4];
        #pragma unroll
        for (int mt = 0; mt < 4; ++mt) af[mt] = *(const bf16x8*)&As[wm + 16 * mt + m16][8 * quad];
        #pragma unroll
        for (int nt = 0; nt < 4; ++nt) bf_[nt] = *(const bf16x8*)&Bs[wn + 16 * nt + m16][8 * quad];
        #pragma unroll
        for (int mt = 0; mt < 4; ++mt)
            #pragma unroll
            for (int nt = 0; nt < 4; ++nt)
                acc[mt][nt] = __builtin_amdgcn_mfma_f32_16x16x32_bf16(af[mt], bf_[nt], acc[mt][nt], 0, 0, 0);
    }
    #pragma unroll
    for (int mt = 0; mt < 4; ++mt)
        #pragma unroll
        for (int nt = 0; nt < 4; ++nt)
            #pragma unroll
            for (int reg = 0; reg < 4; ++reg)
                out[(size_t)(m0 + wm + 16 * mt + 4 * quad + reg) * 1024 + n0 + wn + 16 * nt + m16] =
                    acc[mt][nt][reg];
}

// ============================================================================
extern "C" void kernel_launch(void* const* d_in, const int* in_sizes, int n_in,
                              void* d_out, int out_size, void* d_ws, size_t ws_size,
                              hipStream_t stream) {
    (void)in_sizes; (void)n_in; (void)out_size; (void)ws_size;
    const float* x    = (const float*)d_in[0];
    const int*   pid  = (const int*)  d_in[1];
    const float* cosb = (const float*)d_in[2];
    const float* sinb = (const float*)d_in[3];
    const float* rq   = (const float*)d_in[4];
    const float* rk   = (const float*)d_in[5];
    const float* rv   = (const float*)d_in[6];
    const float* qw1  = (const float*)d_in[7];
    const float* qw2  = (const float*)d_in[8];
    const float* kw1  = (const float*)d_in[9];
    const float* kw2  = (const float*)d_in[10];
    const float* vw1  = (const float*)d_in[11];
    const float* vw2  = (const float*)d_in[12];
    const float* ow   = (const float*)d_in[13];
    float* out = (float*)d_out;

    const size_t MB = 1u << 20;
    char* wsb = (char*)d_ws;
    u16* qb   = (u16*)(wsb + 0 * MB);      // 8 MB  bf16 [B,H,T,D]
    u16* kb   = (u16*)(wsb + 8 * MB);      // 8 MB
    u16* vb   = (u16*)(wsb + 16 * MB);     // 8 MB
    u16* aobf = (u16*)(wsb + 24 * MB);     // 8 MB  bf16 [B,T,C]
    u16* owbf = (u16*)(wsb + 32 * MB);     // 2 MB  bf16 o_w
    unsigned int* idxbuf = (unsigned int*)(wsb + 34 * MB);       // 6 MB
    float2*       wtbuf  = (float2*)(wsb + 41 * MB);             // 12 MB
    unsigned int* counts = (unsigned int*)(wsb + 54 * MB);       // 768 B

    hipMemsetAsync(counts, 0, 1024, stream);

    hipLaunchKernelGGL(router_kernel, dim3(256), dim3(256), 0, stream,
                       x, rq, rk, rv, counts, idxbuf, wtbuf);
    hipLaunchKernelGGL(cvt_bf16_kernel, dim3(1024), dim3(256), 0, stream,
                       ow, owbf, 1024 * 1024 / 4);
    hipLaunchKernelGGL(expert_kernel, dim3(84 * CH), dim3(768), 0, stream,
                       x, pid, cosb, sinb, qw1, qw2, kw1, kw2, vw1, vw2,
                       counts, idxbuf, wtbuf, qb, kb, vb);
    hipLaunchKernelGGL(attn_kernel, dim3(1024), dim3(256), 0, stream,
                       qb, kb, vb, aobf);
    hipLaunchKernelGGL(oproj_kernel, dim3(256), dim3(256), 0, stream,
                       aobf, owbf, out);
}

// Round 9
// 273.621 us; speedup vs baseline: 1.0522x; 1.0522x over previous
//
#include <hip/hip_runtime.h>
#include <math.h>

#define BB 4
#define TT 1024
#define CCH 1024
#define HH 16
#define DD 64
#define EE 8
#define HID 128
#define CAP 8192    // entries per (proj,pair) list; mean is 65536/28 ~= 2340
#define GEXP 252    // expert grid size (blocks allocated by sched_kernel)

typedef unsigned short u16;
typedef short bf16x8 __attribute__((ext_vector_type(8)));
typedef float f32x4 __attribute__((ext_vector_type(4)));

__device__ __forceinline__ u16 f2bf(float f) {
    unsigned int u = __float_as_uint(f);
    unsigned int r = (u + 0x7FFFu + ((u >> 16) & 1u)) >> 16;   // RNE
    return (u16)r;
}

// ============================================================================
// Kernel 1: router. One thread per token-head g = (b*T+t)*16+h; fp32-exact
// top-2 of 8. Tokens binned by (proj, expert-PAIR): pe = p*64 + lo*8 + hi.
// ============================================================================
__global__ __launch_bounds__(256) void router_kernel(
    const float* __restrict__ x,
    const float* __restrict__ rq, const float* __restrict__ rk, const float* __restrict__ rv,
    unsigned int* __restrict__ counts,
    unsigned int* __restrict__ idxbuf, float2* __restrict__ wtbuf)
{
    const int tid = threadIdx.x;
    const unsigned int g = blockIdx.x * 256 + tid;

    __shared__ float rS[3][64][8];
    __shared__ int lcnt[192];
    __shared__ int lbase[192];

    for (int i = tid; i < 1536; i += 256) {
        int p = i >> 9, rem = i & 511;
        const float* rp = (p == 0) ? rq : (p == 1) ? rk : rv;
        rS[p][rem >> 3][rem & 7] = rp[rem];
    }
    if (tid < 192) lcnt[tid] = 0;
    __syncthreads();

    float lg[3][8];
    #pragma unroll
    for (int p = 0; p < 3; ++p)
        #pragma unroll
        for (int e = 0; e < 8; ++e) lg[p][e] = 0.f;

    const float* xr = x + (size_t)g * 64;
    for (int i4 = 0; i4 < 16; ++i4) {
        float4 xv = ((const float4*)xr)[i4];
        float xa[4] = {xv.x, xv.y, xv.z, xv.w};
        #pragma unroll
        for (int m = 0; m < 4; ++m) {
            int d = i4 * 4 + m;
            #pragma unroll
            for (int p = 0; p < 3; ++p) {
                float4 r0 = *(const float4*)&rS[p][d][0];
                float4 r1 = *(const float4*)&rS[p][d][4];
                lg[p][0] += xa[m] * r0.x; lg[p][1] += xa[m] * r0.y;
                lg[p][2] += xa[m] * r0.z; lg[p][3] += xa[m] * r0.w;
                lg[p][4] += xa[m] * r1.x; lg[p][5] += xa[m] * r1.y;
                lg[p][6] += xa[m] * r1.z; lg[p][7] += xa[m] * r1.w;
            }
        }
    }

    int ppe[3]; float2 pw[3]; int slot[3];
    #pragma unroll
    for (int p = 0; p < 3; ++p) {
        int i1 = 0; float v1 = lg[p][0];
        #pragma unroll
        for (int e = 1; e < 8; ++e) { if (lg[p][e] > v1) { v1 = lg[p][e]; i1 = e; } }
        int i2 = -1; float v2 = -3.402823466e38f;
        #pragma unroll
        for (int e = 0; e < 8; ++e) { if (e != i1 && lg[p][e] > v2) { v2 = lg[p][e]; i2 = e; } }
        float z = __expf(v2 - v1);
        float inv = 1.f / (1.f + z);
        float wa = inv, wb = z * inv;
        int lo = min(i1, i2), hi = max(i1, i2);
        float wlo = (i1 < i2) ? wa : wb;
        float whi = (i1 < i2) ? wb : wa;
        int pel = p * 64 + lo * 8 + hi;
        ppe[p] = pel; pw[p] = make_float2(wlo, whi);
        slot[p] = atomicAdd(&lcnt[pel], 1);
    }
    __syncthreads();
    if (tid < 192) {
        int c = lcnt[tid];
        lbase[tid] = c ? (int)atomicAdd(&counts[tid], (unsigned int)c) : 0;
    }
    __syncthreads();
    #pragma unroll
    for (int p = 0; p < 3; ++p) {
        int pos = lbase[ppe[p]] + slot[p];
        if (pos < CAP) {
            idxbuf[ppe[p] * CAP + pos] = g;
            wtbuf[ppe[p] * CAP + pos]  = pw[p];
        }
    }
}

// ============================================================================
// Kernel 1b: scheduler. Allocates GEXP blocks across the 84 (proj,pair)
// lists proportionally to subtile count (largest-remainder; every nonzero
// list gets >= 1 block). Removes the list-size tail that pinned expert_kernel
// at ~96 us (R8 occupancy 16% vs 37% resident = imbalance signature).
// ============================================================================
__global__ __launch_bounds__(128) void sched_kernel(
    const unsigned int* __restrict__ counts, unsigned int* __restrict__ blockinfo)
{
    const int tid = threadIdx.x;
    __shared__ int nsub[84];
    __shared__ int extra[84];
    __shared__ int frac[84];
    __shared__ int alloc[84];
    __shared__ int startS[84];
    __shared__ int nnzS, totalS, rem2S;

    if (tid < 84) {
        int p = tid / 28, q = tid - 28 * p, lo = 0;
        while (q >= 7 - lo) { q -= 7 - lo; ++lo; }
        int hi = lo + 1 + q;
        int n = (int)counts[p * 64 + lo * 8 + hi];
        if (n > CAP) n = CAP;
        nsub[tid] = (n + 31) >> 5;
    }
    __syncthreads();
    if (tid == 0) {
        int tot = 0, nz = 0;
        for (int i = 0; i < 84; ++i) { tot += nsub[i]; nz += (nsub[i] > 0); }
        totalS = tot; nnzS = nz;
    }
    __syncthreads();
    const int R = GEXP - nnzS;
    if (tid < 84) {
        if (nsub[tid] > 0) {
            int e = (int)(((long long)nsub[tid] * R) / totalS);
            extra[tid] = e;
            frac[tid] = nsub[tid] * R - e * totalS;
        } else { extra[tid] = 0; frac[tid] = -1; }
    }
    __syncthreads();
    if (tid == 0) {
        int se = 0;
        for (int i = 0; i < 84; ++i) se += extra[i];
        rem2S = GEXP - nnzS - se;
    }
    __syncthreads();
    if (tid < 84) {
        if (nsub[tid] > 0) {
            int rank = 0;
            for (int j = 0; j < 84; ++j)
                if (nsub[j] > 0 && (frac[j] > frac[tid] || (frac[j] == frac[tid] && j < tid))) ++rank;
            alloc[tid] = 1 + extra[tid] + (rank < rem2S ? 1 : 0);
        } else alloc[tid] = 0;
    }
    __syncthreads();
    if (tid == 0) {
        int s = 0;
        for (int i = 0; i < 84; ++i) { startS[i] = s; s += alloc[i]; }
    }
    __syncthreads();
    if (tid < 84) {
        int a = alloc[tid], st = startS[tid];
        for (int c = 0; c < a; ++c)
            blockinfo[st + c] = (unsigned)tid | ((unsigned)c << 8) | ((unsigned)a << 20);
    }
}

// ============================================================================
// Kernel 2: pair-grouped expert MLP, bf16 MFMA, wave-independent.
// GEXP blocks, assignment from sched_kernel's blockinfo table. 768 threads
// = 12 waves; 32-token subtiles per wave (R8 compute core, passing).
// ============================================================================
__global__ __launch_bounds__(768) void expert_kernel(
    const float* __restrict__ x, const int* __restrict__ pos_ids,
    const float* __restrict__ cosb, const float* __restrict__ sinb,
    const float* __restrict__ w1q, const float* __restrict__ w2q,
    const float* __restrict__ w1k, const float* __restrict__ w2k,
    const float* __restrict__ w1v, const float* __restrict__ w2v,
    const unsigned int* __restrict__ counts,
    const unsigned int* __restrict__ idxbuf, const float2* __restrict__ wtbuf,
    const unsigned int* __restrict__ blockinfo,
    u16* __restrict__ qb, u16* __restrict__ kb, u16* __restrict__ vb)
{
    const int tid = threadIdx.x;
    const unsigned int info = blockinfo[blockIdx.x];
    const int pe84 = info & 255;
    const int chunk = (info >> 8) & 0xFFF;
    const int nch = info >> 20;
    const int p = pe84 / 28;
    int q28 = pe84 - p * 28;
    int lo = 0;
    while (q28 >= 7 - lo) { q28 -= 7 - lo; ++lo; }
    const int hi = lo + 1 + q28;
    const int pe = p * 64 + lo * 8 + hi;

    int n = (int)counts[pe]; if (n == 0) return; if (n > CAP) n = CAP;

    const float* w1base = (p == 0) ? w1q : (p == 1) ? w1k : w1v;
    const float* w2base = (p == 0) ? w2q : (p == 1) ? w2k : w2v;
    u16* outp = (p == 0) ? qb : (p == 1) ? kb : vb;
    const unsigned int* il = idxbuf + pe * CAP;
    const float2* wl = wtbuf + pe * CAP;

    __shared__ u16 w1t[2][128][72];    // [e][f][d]  B-operand GEMM1   36.9 KB
    __shared__ u16 w2t[2][64][136];    // [e][g][f]  B-operand GEMM2   34.8 KB
    __shared__ u16 hsw[12][32][40];    // per-wave gelu scratch        30.7 KB

    // ---- stage both experts' weights, bf16-transposed (once) ----
    #pragma unroll
    for (int e = 0; e < 2; ++e) {
        int ex = e ? hi : lo;
        const float* w1 = w1base + ex * 64 * 128;   // [d][f]
        const float* w2 = w2base + ex * 128 * 64;   // [f][g]
        for (int i = tid; i < 8192; i += 768)
            w1t[e][i & 127][i >> 7] = f2bf(w1[i]);
        for (int i = tid; i < 8192; i += 768)
            w2t[e][i & 63][i >> 6] = f2bf(w2[i]);
    }
    __syncthreads();

    const int lane = tid & 63, w = tid >> 6, quad = lane >> 4, m16 = lane & 15;
    const int wid = chunk * 12 + w;
    const int WRK = nch * 12;
    const int nsub = (n + 31) >> 5;

    for (int s = wid; s < nsub; s += WRK) {
        const int base = s * 32;
        // ---- lanes 0..31: per-token metadata; broadcast via shfl ----
        unsigned int gtok = 0, obase = 0; float wlo_ = 0.f, whi_ = 0.f;
        int posv = 0, valid = 0;
        if (lane < 32) {
            int j = base + lane;
            valid = (j < n);
            int jc = valid ? j : (n - 1);
            gtok = il[jc];
            float2 wv = wl[jc];
            wlo_ = valid ? wv.x : 0.f; whi_ = valid ? wv.y : 0.f;
            unsigned int b_ = gtok >> 14, h_ = gtok & 15, t_ = (gtok >> 4) & 1023;
            obase = ((b_ * 16 + h_) * 1024 + t_) * 64;
            posv = pos_ids[b_ * 1024 + t_];
        }

        // ---- A-frags for both 16-token M-tiles ----
        bf16x8 Afr[2][2];
        #pragma unroll
        for (int mt2 = 0; mt2 < 2; ++mt2) {
            unsigned int gm = (unsigned int)__shfl((int)gtok, mt2 * 16 + m16, 64);
            const float* xr = x + (size_t)gm * 64 + 8 * quad;
            float4 xa0 = *(const float4*)(xr);
            float4 xa1 = *(const float4*)(xr + 4);
            float4 xb0 = *(const float4*)(xr + 32);
            float4 xb1 = *(const float4*)(xr + 36);
            bf16x8 A0, A1;
            A0[0] = (short)f2bf(xa0.x); A0[1] = (short)f2bf(xa0.y);
            A0[2] = (short)f2bf(xa0.z); A0[3] = (short)f2bf(xa0.w);
            A0[4] = (short)f2bf(xa1.x); A0[5] = (short)f2bf(xa1.y);
            A0[6] = (short)f2bf(xa1.z); A0[7] = (short)f2bf(xa1.w);
            A1[0] = (short)f2bf(xb0.x); A1[1] = (short)f2bf(xb0.y);
            A1[2] = (short)f2bf(xb0.z); A1[3] = (short)f2bf(xb0.w);
            A1[4] = (short)f2bf(xb1.x); A1[5] = (short)f2bf(xb1.y);
            A1[6] = (short)f2bf(xb1.z); A1[7] = (short)f2bf(xb1.w);
            Afr[mt2][0] = A0; Afr[mt2][1] = A1;
        }

        f32x4 acc2[2][2][4];   // [e][Mtile][nt]
        #pragma unroll
        for (int e = 0; e < 2; ++e)
            #pragma unroll
            for (int mt2 = 0; mt2 < 2; ++mt2)
                #pragma unroll
                for (int nt = 0; nt < 4; ++nt) acc2[e][mt2][nt] = (f32x4){0.f, 0.f, 0.f, 0.f};

        #pragma unroll
        for (int e = 0; e < 2; ++e) {
            #pragma unroll
            for (int kk = 0; kk < 4; ++kk) {
                // --- GEMM1 for 32 hidden features (n-tiles 2kk, 2kk+1), both M ---
                int nt0 = 2 * kk, nt1 = 2 * kk + 1;
                bf16x8 b0a = *(const bf16x8*)&w1t[e][16 * nt0 + m16][8 * quad];
                bf16x8 b0b = *(const bf16x8*)&w1t[e][16 * nt0 + m16][32 + 8 * quad];
                bf16x8 b1a = *(const bf16x8*)&w1t[e][16 * nt1 + m16][8 * quad];
                bf16x8 b1b = *(const bf16x8*)&w1t[e][16 * nt1 + m16][32 + 8 * quad];
                #pragma unroll
                for (int mt2 = 0; mt2 < 2; ++mt2) {
                    f32x4 c0 = (f32x4){0.f, 0.f, 0.f, 0.f};
                    f32x4 c1 = (f32x4){0.f, 0.f, 0.f, 0.f};
                    c0 = __builtin_amdgcn_mfma_f32_16x16x32_bf16(Afr[mt2][0], b0a, c0, 0, 0, 0);
                    c0 = __builtin_amdgcn_mfma_f32_16x16x32_bf16(Afr[mt2][1], b0b, c0, 0, 0, 0);
                    c1 = __builtin_amdgcn_mfma_f32_16x16x32_bf16(Afr[mt2][0], b1a, c1, 0, 0, 0);
                    c1 = __builtin_amdgcn_mfma_f32_16x16x32_bf16(Afr[mt2][1], b1b, c1, 0, 0, 0);
                    #pragma unroll
                    for (int r = 0; r < 4; ++r) {
                        float z = c0[r];
                        float u = 1.5957691216057308f * (z + 0.044715f * z * z * z);
                        hsw[w][mt2 * 16 + 4 * quad + r][m16] = f2bf(z / (1.f + __expf(-u)));
                        float z2 = c1[r];
                        float u2 = 1.5957691216057308f * (z2 + 0.044715f * z2 * z2 * z2);
                        hsw[w][mt2 * 16 + 4 * quad + r][16 + m16] = f2bf(z2 / (1.f + __expf(-u2)));
                    }
                }
                // --- GEMM2 partial: B-frag loaded once, used by both M-tiles ---
                bf16x8 A2_0 = *(const bf16x8*)&hsw[w][m16][8 * quad];
                bf16x8 A2_1 = *(const bf16x8*)&hsw[w][16 + m16][8 * quad];
                #pragma unroll
                for (int nt2 = 0; nt2 < 4; ++nt2) {
                    bf16x8 b2 = *(const bf16x8*)&w2t[e][16 * nt2 + m16][32 * kk + 8 * quad];
                    acc2[e][0][nt2] = __builtin_amdgcn_mfma_f32_16x16x32_bf16(A2_0, b2, acc2[e][0][nt2], 0, 0, 0);
                    acc2[e][1][nt2] = __builtin_amdgcn_mfma_f32_16x16x32_bf16(A2_1, b2, acc2[e][1][nt2], 0, 0, 0);
                }
            }
        }

        // ---- combine experts + RoPE + store (token = mt2*16 + 4*quad + r) ----
        #pragma unroll
        for (int mt2 = 0; mt2 < 2; ++mt2) {
            #pragma unroll
            for (int r = 0; r < 4; ++r) {
                int tk = mt2 * 16 + 4 * quad + r;
                float wlo_r = __shfl(wlo_, tk, 64);
                float whi_r = __shfl(whi_, tk, 64);
                int   pos_r = __shfl(posv, tk, 64);
                unsigned int ob = (unsigned int)__shfl((int)obase, tk, 64);
                int   val_r = __shfl(valid, tk, 64);
                if (p < 2) {
                    #pragma unroll
                    for (int ntp = 0; ntp < 2; ++ntp) {
                        int d = 16 * ntp + m16;
                        float v1 = wlo_r * acc2[0][mt2][ntp][r]     + whi_r * acc2[1][mt2][ntp][r];
                        float v2 = wlo_r * acc2[0][mt2][ntp + 2][r] + whi_r * acc2[1][mt2][ntp + 2][r];
                        float cd = cosb[pos_r * 64 + d];
                        float sd = sinb[pos_r * 64 + d];
                        if (val_r) {
                            outp[ob + d]      = f2bf(v1 * cd - v2 * sd);
                            outp[ob + d + 32] = f2bf(v2 * cd + v1 * sd);
                        }
                    }
                } else {
                    #pragma unroll
                    for (int nt = 0; nt < 4; ++nt) {
                        float v = wlo_r * acc2[0][mt2][nt][r] + whi_r * acc2[1][mt2][nt][r];
                        if (val_r) outp[ob + 16 * nt + m16] = f2bf(v);
                    }
                }
            }
        }
    }
}

// ============================================================================
// Kernel 3: fp32 -> bf16 convert (for o_w)
// ============================================================================
__global__ __launch_bounds__(256) void cvt_bf16_kernel(
    const float* __restrict__ in, u16* __restrict__ out, int n4)
{
    int i = blockIdx.x * 256 + threadIdx.x;
    if (i >= n4) return;
    float4 v = ((const float4*)in)[i];
    unsigned int lov = (unsigned int)f2bf(v.x) | ((unsigned int)f2bf(v.y) << 16);
    unsigned int hiv = (unsigned int)f2bf(v.z) | ((unsigned int)f2bf(v.w) << 16);
    ((uint2*)out)[i] = make_uint2(lov, hiv);
}

// ============================================================================
// Kernel 4: flash attention, bf16 MFMA (R7-verbatim: paired q-tiles
// (i, 15-i), grid 512, running-max softmax, Q A-frags from global).
// ============================================================================
__global__ __launch_bounds__(256) void attn_kernel(
    const u16* __restrict__ qbp, const u16* __restrict__ kbp,
    const u16* __restrict__ vbp, u16* __restrict__ ao)
{
    const int tid = threadIdx.x;
    const int i8 = blockIdx.x & 7;
    const int plane_i = blockIdx.x >> 3;           // 64 planes
    const int h = plane_i & 15, b = plane_i >> 4;
    const size_t plane = (size_t)plane_i * 1024 * 64;
    const u16* qp = qbp + plane;
    const u16* kp = kbp + plane;
    const u16* vp = vbp + plane;

    const int w = tid >> 6, lane = tid & 63, quad = lane >> 4, m16 = lane & 15;

    __shared__ u16 Ks[64][72];
    __shared__ u16 Vt[64][72];        // [d][kj]
    __shared__ u16 Ps[4][16][72];     // per-wave P scratch

    #pragma unroll 1
    for (int half = 0; half < 2; ++half) {
        const int qt = half ? (15 - i8) : i8;
        const int q0 = qt * 64;

        const u16* qrow = &qp[(size_t)(q0 + 16 * w + m16) * 64 + 8 * quad];
        bf16x8 aq0 = *(const bf16x8*)(qrow);
        bf16x8 aq1 = *(const bf16x8*)(qrow + 32);

        float m_r[4], l_r[4];
        #pragma unroll
        for (int i = 0; i < 4; ++i) { m_r[i] = -1e30f; l_r[i] = 0.f; }
        f32x4 oacc[4];
        #pragma unroll
        for (int i = 0; i < 4; ++i) oacc[i] = (f32x4){0.f, 0.f, 0.f, 0.f};

        for (int kt = 0; kt <= qt; ++kt) {
            const int k0 = kt * 64;
            __syncthreads();
            {
                int row = tid >> 2, seg = tid & 3;
                const uint4* src = (const uint4*)&kp[(size_t)(k0 + row) * 64 + seg * 16];
                uint4 v0 = src[0], v1 = src[1];
                uint4* dst = (uint4*)&Ks[row][seg * 16];
                dst[0] = v0; dst[1] = v1;
            }
            {
                int kj = tid & 63, dg = tid >> 6;
                #pragma unroll
                for (int pp = 0; pp < 4; ++pp) {
                    int d0 = dg * 4 + pp * 16;
                    ushort4 v = *(const ushort4*)&vp[(size_t)(k0 + kj) * 64 + d0];
                    Vt[d0 + 0][kj] = v.x; Vt[d0 + 1][kj] = v.y;
                    Vt[d0 + 2][kj] = v.z; Vt[d0 + 3][kj] = v.w;
                }
            }
            __syncthreads();

            f32x4 sv[4];
            #pragma unroll
            for (int ct = 0; ct < 4; ++ct) {
                bf16x8 bk0 = *(const bf16x8*)&Ks[16 * ct + m16][8 * quad];
                bf16x8 bk1 = *(const bf16x8*)&Ks[16 * ct + m16][32 + 8 * quad];
                f32x4 acc = (f32x4){0.f, 0.f, 0.f, 0.f};
                acc = __builtin_amdgcn_mfma_f32_16x16x32_bf16(aq0, bk0, acc, 0, 0, 0);
                acc = __builtin_amdgcn_mfma_f32_16x16x32_bf16(aq1, bk1, acc, 0, 0, 0);
                sv[ct] = acc;
            }

            float s[4][4];
            const bool diag = (kt == qt);
            #pragma unroll
            for (int ct = 0; ct < 4; ++ct)
                #pragma unroll
                for (int reg = 0; reg < 4; ++reg) {
                    float v = sv[ct][reg] * 0.125f;
                    if (diag) {
                        int col = 16 * ct + m16;
                        int row = 16 * w + 4 * quad + reg;
                        if (col > row) v = -1e30f;
                    }
                    s[ct][reg] = v;
                }

            float nm[4], al[4];
            #pragma unroll
            for (int reg = 0; reg < 4; ++reg) {
                float rm = fmaxf(fmaxf(s[0][reg], s[1][reg]), fmaxf(s[2][reg], s[3][reg]));
                #pragma unroll
                for (int off = 1; off < 16; off <<= 1) rm = fmaxf(rm, __shfl_xor(rm, off, 16));
                float mn = fmaxf(m_r[reg], rm);
                nm[reg] = mn;
                al[reg] = __expf(m_r[reg] - mn);
            }
            #pragma unroll
            for (int reg = 0; reg < 4; ++reg) {
                float sum = 0.f;
                #pragma unroll
                for (int ct = 0; ct < 4; ++ct) {
                    float pv = __expf(s[ct][reg] - nm[reg]);
                    s[ct][reg] = pv;
                    sum += pv;
                }
                #pragma unroll
                for (int off = 1; off < 16; off <<= 1) sum += __shfl_xor(sum, off, 16);
                l_r[reg] = l_r[reg] * al[reg] + sum;
                m_r[reg] = nm[reg];
            }

            #pragma unroll
            for (int ct = 0; ct < 4; ++ct)
                #pragma unroll
                for (int reg = 0; reg < 4; ++reg)
                    Ps[w][4 * quad + reg][16 * ct + m16] = f2bf(s[ct][reg]);

            #pragma unroll
            for (int dt = 0; dt < 4; ++dt)
                #pragma unroll
                for (int reg = 0; reg < 4; ++reg) oacc[dt][reg] *= al[reg];

            bf16x8 ap0 = *(const bf16x8*)&Ps[w][m16][8 * quad];
            bf16x8 ap1 = *(const bf16x8*)&Ps[w][m16][32 + 8 * quad];
            #pragma unroll
            for (int dt = 0; dt < 4; ++dt) {
                bf16x8 bv0 = *(const bf16x8*)&Vt[16 * dt + m16][8 * quad];
                bf16x8 bv1 = *(const bf16x8*)&Vt[16 * dt + m16][32 + 8 * quad];
                oacc[dt] = __builtin_amdgcn_mfma_f32_16x16x32_bf16(ap0, bv0, oacc[dt], 0, 0, 0);
                oacc[dt] = __builtin_amdgcn_mfma_f32_16x16x32_bf16(ap1, bv1, oacc[dt], 0, 0, 0);
            }
        }

        #pragma unroll
        for (int reg = 0; reg < 4; ++reg) {
            float linv = 1.f / l_r[reg];
            int row = q0 + 16 * w + 4 * quad + reg;
            size_t base = ((size_t)(b * 1024) + row) * 1024 + h * 64;
            #pragma unroll
            for (int dt = 0; dt < 4; ++dt)
                ao[base + 16 * dt + m16] = f2bf(oacc[dt][reg] * linv);
        }
    }
}

// ============================================================================
// Kernel 5: output projection, bf16 MFMA gemm_bt. 128x128 tile, BK=32
// (R4-verbatim, known good).
// ============================================================================
__global__ __launch_bounds__(256) void oproj_kernel(
    const u16* __restrict__ A, const u16* __restrict__ Bw,
    float* __restrict__ out)
{
    const int tid = threadIdx.x;
    const int bn = blockIdx.x & 7;
    const int bm = blockIdx.x >> 3;
    const int m0 = bm * 128, n0 = bn * 128;
    const int w = tid >> 6, lane = tid & 63, quad = lane >> 4, m16 = lane & 15;
    const int wm = (w >> 1) * 64, wn = (w & 1) * 64;

    __shared__ u16 As[128][32];
    __shared__ u16 Bs[128][32];

    f32x4 acc[4][4];
    #pragma unroll
    for (int mt = 0; mt < 4; ++mt)
        #pragma unroll
        for (int nt = 0; nt < 4; ++nt) acc[mt][nt] = (f32x4){0.f, 0.f, 0.f, 0.f};

    for (int k0 = 0; k0 < 1024; k0 += 32) {
        __syncthreads();
        {
            int row = tid >> 1, sg = (tid & 1) * 16;
            const uint4* srcA = (const uint4*)&A[(size_t)(m0 + row) * 1024 + k0 + sg];
            uint4 a0 = srcA[0], a1 = srcA[1];
            uint4* dstA = (uint4*)&As[row][sg];
            dstA[0] = a0; dstA[1] = a1;
            const uint4* srcB = (const uint4*)&Bw[(size_t)(n0 + row) * 1024 + k0 + sg];
            uint4 b0 = srcB[0], b1 = srcB[1];
            uint4* dstB = (uint4*)&Bs[row][sg];
            dstB[0] = b0; dstB[1] = b1;
        }
        __syncthreads();
        bf16x8 af[4], bf_[4];
        #pragma unroll
        for (int mt = 0; mt < 4; ++mt) af[mt] = *(const bf16x8*)&As[wm + 16 * mt + m16][8 * quad];
        #pragma unroll
        for (int nt = 0; nt < 4; ++nt) bf_[nt] = *(const bf16x8*)&Bs[wn + 16 * nt + m16][8 * quad];
        #pragma unroll
        for (int mt = 0; mt < 4; ++mt)
            #pragma unroll
            for (int nt = 0; nt < 4; ++nt)
                acc[mt][nt] = __builtin_amdgcn_mfma_f32_16x16x32_bf16(af[mt], bf_[nt], acc[mt][nt], 0, 0, 0);
    }
    #pragma unroll
    for (int mt = 0; mt < 4; ++mt)
        #pragma unroll
        for (int nt = 0; nt < 4; ++nt)
            #pragma unroll
            for (int reg = 0; reg < 4; ++reg)
                out[(size_t)(m0 + wm + 16 * mt + 4 * quad + reg) * 1024 + n0 + wn + 16 * nt + m16] =
                    acc[mt][nt][reg];
}

// ============================================================================
extern "C" void kernel_launch(void* const* d_in, const int* in_sizes, int n_in,
                              void* d_out, int out_size, void* d_ws, size_t ws_size,
                              hipStream_t stream) {
    (void)in_sizes; (void)n_in; (void)out_size; (void)ws_size;
    const float* x    = (const float*)d_in[0];
    const int*   pid  = (const int*)  d_in[1];
    const float* cosb = (const float*)d_in[2];
    const float* sinb = (const float*)d_in[3];
    const float* rq   = (const float*)d_in[4];
    const float* rk   = (const float*)d_in[5];
    const float* rv   = (const float*)d_in[6];
    const float* qw1  = (const float*)d_in[7];
    const float* qw2  = (const float*)d_in[8];
    const float* kw1  = (const float*)d_in[9];
    const float* kw2  = (const float*)d_in[10];
    const float* vw1  = (const float*)d_in[11];
    const float* vw2  = (const float*)d_in[12];
    const float* ow   = (const float*)d_in[13];
    float* out = (float*)d_out;

    const size_t MB = 1u << 20;
    char* wsb = (char*)d_ws;
    u16* qb   = (u16*)(wsb + 0 * MB);      // 8 MB  bf16 [B,H,T,D]
    u16* kb   = (u16*)(wsb + 8 * MB);      // 8 MB
    u16* vb   = (u16*)(wsb + 16 * MB);     // 8 MB
    u16* aobf = (u16*)(wsb + 24 * MB);     // 8 MB  bf16 [B,T,C]
    u16* owbf = (u16*)(wsb + 32 * MB);     // 2 MB  bf16 o_w
    unsigned int* idxbuf = (unsigned int*)(wsb + 34 * MB);       // 6 MB
    float2*       wtbuf  = (float2*)(wsb + 41 * MB);             // 12 MB
    unsigned int* counts = (unsigned int*)(wsb + 54 * MB);       // 768 B
    unsigned int* blockinfo = (unsigned int*)(wsb + 54 * MB + 4096); // 1 KB

    hipMemsetAsync(counts, 0, 1024, stream);

    hipLaunchKernelGGL(router_kernel, dim3(256), dim3(256), 0, stream,
                       x, rq, rk, rv, counts, idxbuf, wtbuf);
    hipLaunchKernelGGL(sched_kernel, dim3(1), dim3(128), 0, stream,
                       counts, blockinfo);
    hipLaunchKernelGGL(cvt_bf16_kernel, dim3(1024), dim3(256), 0, stream,
                       ow, owbf, 1024 * 1024 / 4);
    hipLaunchKernelGGL(expert_kernel, dim3(GEXP), dim3(768), 0, stream,
                       x, pid, cosb, sinb, qw1, qw2, kw1, kw2, vw1, vw2,
                       counts, idxbuf, wtbuf, blockinfo, qb, kb, vb);
    hipLaunchKernelGGL(attn_kernel, dim3(512), dim3(256), 0, stream,
                       qb, kb, vb, aobf);
    hipLaunchKernelGGL(oproj_kernel, dim3(256), dim3(256), 0, stream,
                       aobf, owbf, out);
}

// Round 10
// 258.567 us; speedup vs baseline: 1.1135x; 1.0582x over previous
//
#include <hip/hip_runtime.h>
#include <math.h>

#define BB 4
#define TT 1024
#define CCH 1024
#define HH 16
#define DD 64
#define EE 8
#define HID 128
#define CAP 8192    // entries per (proj,pair) list; mean is 65536/28 ~= 2340
#define GEXP 252    // expert grid size (blocks allocated by sched_kernel)

typedef unsigned short u16;
typedef short bf16x8 __attribute__((ext_vector_type(8)));
typedef float f32x4 __attribute__((ext_vector_type(4)));

__device__ __forceinline__ u16 f2bf(float f) {          // RNE (final stores)
    unsigned int u = __float_as_uint(f);
    unsigned int r = (u + 0x7FFFu + ((u >> 16) & 1u)) >> 16;
    return (u16)r;
}
__device__ __forceinline__ u16 f2bf_f(float f) {        // fast round (intermediates)
    return (u16)((__float_as_uint(f) + 0x8000u) >> 16);
}
// gelu(z) = z * sigmoid(1.59576912*(z + 0.044715 z^3)); fast div via v_rcp
__device__ __forceinline__ float gelu_fast(float z) {
    float t = z * z;
    float wn = __builtin_fmaf(t, -0.07135481283f, -1.5957691216f);
    float e = __expf(z * wn);
    return __fdividef(z, 1.f + e);
}

// ============================================================================
// Kernel 1: router. One thread per token-head g = (b*T+t)*16+h; fp32-exact
// top-2 of 8. Tokens binned by (proj, expert-PAIR): pe = p*64 + lo*8 + hi.
// ============================================================================
__global__ __launch_bounds__(256) void router_kernel(
    const float* __restrict__ x,
    const float* __restrict__ rq, const float* __restrict__ rk, const float* __restrict__ rv,
    unsigned int* __restrict__ counts,
    unsigned int* __restrict__ idxbuf, float2* __restrict__ wtbuf)
{
    const int tid = threadIdx.x;
    const unsigned int g = blockIdx.x * 256 + tid;

    __shared__ float rS[3][64][8];
    __shared__ int lcnt[192];
    __shared__ int lbase[192];

    for (int i = tid; i < 1536; i += 256) {
        int p = i >> 9, rem = i & 511;
        const float* rp = (p == 0) ? rq : (p == 1) ? rk : rv;
        rS[p][rem >> 3][rem & 7] = rp[rem];
    }
    if (tid < 192) lcnt[tid] = 0;
    __syncthreads();

    float lg[3][8];
    #pragma unroll
    for (int p = 0; p < 3; ++p)
        #pragma unroll
        for (int e = 0; e < 8; ++e) lg[p][e] = 0.f;

    const float* xr = x + (size_t)g * 64;
    for (int i4 = 0; i4 < 16; ++i4) {
        float4 xv = ((const float4*)xr)[i4];
        float xa[4] = {xv.x, xv.y, xv.z, xv.w};
        #pragma unroll
        for (int m = 0; m < 4; ++m) {
            int d = i4 * 4 + m;
            #pragma unroll
            for (int p = 0; p < 3; ++p) {
                float4 r0 = *(const float4*)&rS[p][d][0];
                float4 r1 = *(const float4*)&rS[p][d][4];
                lg[p][0] += xa[m] * r0.x; lg[p][1] += xa[m] * r0.y;
                lg[p][2] += xa[m] * r0.z; lg[p][3] += xa[m] * r0.w;
                lg[p][4] += xa[m] * r1.x; lg[p][5] += xa[m] * r1.y;
                lg[p][6] += xa[m] * r1.z; lg[p][7] += xa[m] * r1.w;
            }
        }
    }

    int ppe[3]; float2 pw[3]; int slot[3];
    #pragma unroll
    for (int p = 0; p < 3; ++p) {
        int i1 = 0; float v1 = lg[p][0];
        #pragma unroll
        for (int e = 1; e < 8; ++e) { if (lg[p][e] > v1) { v1 = lg[p][e]; i1 = e; } }
        int i2 = -1; float v2 = -3.402823466e38f;
        #pragma unroll
        for (int e = 0; e < 8; ++e) { if (e != i1 && lg[p][e] > v2) { v2 = lg[p][e]; i2 = e; } }
        float z = __expf(v2 - v1);
        float inv = 1.f / (1.f + z);
        float wa = inv, wb = z * inv;
        int lo = min(i1, i2), hi = max(i1, i2);
        float wlo = (i1 < i2) ? wa : wb;
        float whi = (i1 < i2) ? wb : wa;
        int pel = p * 64 + lo * 8 + hi;
        ppe[p] = pel; pw[p] = make_float2(wlo, whi);
        slot[p] = atomicAdd(&lcnt[pel], 1);
    }
    __syncthreads();
    if (tid < 192) {
        int c = lcnt[tid];
        lbase[tid] = c ? (int)atomicAdd(&counts[tid], (unsigned int)c) : 0;
    }
    __syncthreads();
    #pragma unroll
    for (int p = 0; p < 3; ++p) {
        int pos = lbase[ppe[p]] + slot[p];
        if (pos < CAP) {
            idxbuf[ppe[p] * CAP + pos] = g;
            wtbuf[ppe[p] * CAP + pos]  = pw[p];
        }
    }
}

// ============================================================================
// Kernel 1b: scheduler. Allocates GEXP blocks across the 84 (proj,pair)
// lists proportionally to subtile count (largest-remainder).
// ============================================================================
__global__ __launch_bounds__(128) void sched_kernel(
    const unsigned int* __restrict__ counts, unsigned int* __restrict__ blockinfo)
{
    const int tid = threadIdx.x;
    __shared__ int nsub[84];
    __shared__ int extra[84];
    __shared__ int frac[84];
    __shared__ int alloc[84];
    __shared__ int startS[84];
    __shared__ int nnzS, totalS, rem2S;

    if (tid < 84) {
        int p = tid / 28, q = tid - 28 * p, lo = 0;
        while (q >= 7 - lo) { q -= 7 - lo; ++lo; }
        int hi = lo + 1 + q;
        int n = (int)counts[p * 64 + lo * 8 + hi];
        if (n > CAP) n = CAP;
        nsub[tid] = (n + 31) >> 5;
    }
    __syncthreads();
    if (tid == 0) {
        int tot = 0, nz = 0;
        for (int i = 0; i < 84; ++i) { tot += nsub[i]; nz += (nsub[i] > 0); }
        totalS = tot; nnzS = nz;
    }
    __syncthreads();
    const int R = GEXP - nnzS;
    if (tid < 84) {
        if (nsub[tid] > 0) {
            int e = (int)(((long long)nsub[tid] * R) / totalS);
            extra[tid] = e;
            frac[tid] = nsub[tid] * R - e * totalS;
        } else { extra[tid] = 0; frac[tid] = -1; }
    }
    __syncthreads();
    if (tid == 0) {
        int se = 0;
        for (int i = 0; i < 84; ++i) se += extra[i];
        rem2S = GEXP - nnzS - se;
    }
    __syncthreads();
    if (tid < 84) {
        if (nsub[tid] > 0) {
            int rank = 0;
            for (int j = 0; j < 84; ++j)
                if (nsub[j] > 0 && (frac[j] > frac[tid] || (frac[j] == frac[tid] && j < tid))) ++rank;
            alloc[tid] = 1 + extra[tid] + (rank < rem2S ? 1 : 0);
        } else alloc[tid] = 0;
    }
    __syncthreads();
    if (tid == 0) {
        int s = 0;
        for (int i = 0; i < 84; ++i) { startS[i] = s; s += alloc[i]; }
    }
    __syncthreads();
    if (tid < 84) {
        int a = alloc[tid], st = startS[tid];
        for (int c = 0; c < a; ++c)
            blockinfo[st + c] = (unsigned)tid | ((unsigned)c << 8) | ((unsigned)a << 20);
    }
}

// ============================================================================
// Kernel 2: pair-grouped expert MLP, bf16 MFMA, wave-independent.
// GEXP blocks via blockinfo; 768 threads = 12 waves; 32-token subtiles.
// R10: gelu_fast (no IEEE div) + fast f2bf for intermediates.
// ============================================================================
__global__ __launch_bounds__(768) void expert_kernel(
    const float* __restrict__ x, const int* __restrict__ pos_ids,
    const float* __restrict__ cosb, const float* __restrict__ sinb,
    const float* __restrict__ w1q, const float* __restrict__ w2q,
    const float* __restrict__ w1k, const float* __restrict__ w2k,
    const float* __restrict__ w1v, const float* __restrict__ w2v,
    const unsigned int* __restrict__ counts,
    const unsigned int* __restrict__ idxbuf, const float2* __restrict__ wtbuf,
    const unsigned int* __restrict__ blockinfo,
    u16* __restrict__ qb, u16* __restrict__ kb, u16* __restrict__ vb)
{
    const int tid = threadIdx.x;
    const unsigned int info = blockinfo[blockIdx.x];
    const int pe84 = info & 255;
    const int chunk = (info >> 8) & 0xFFF;
    const int nch = info >> 20;
    const int p = pe84 / 28;
    int q28 = pe84 - p * 28;
    int lo = 0;
    while (q28 >= 7 - lo) { q28 -= 7 - lo; ++lo; }
    const int hi = lo + 1 + q28;
    const int pe = p * 64 + lo * 8 + hi;

    int n = (int)counts[pe]; if (n == 0) return; if (n > CAP) n = CAP;

    const float* w1base = (p == 0) ? w1q : (p == 1) ? w1k : w1v;
    const float* w2base = (p == 0) ? w2q : (p == 1) ? w2k : w2v;
    u16* outp = (p == 0) ? qb : (p == 1) ? kb : vb;
    const unsigned int* il = idxbuf + pe * CAP;
    const float2* wl = wtbuf + pe * CAP;

    __shared__ u16 w1t[2][128][72];    // [e][f][d]  B-operand GEMM1   36.9 KB
    __shared__ u16 w2t[2][64][136];    // [e][g][f]  B-operand GEMM2   34.8 KB
    __shared__ u16 hsw[12][32][40];    // per-wave gelu scratch        30.7 KB

    #pragma unroll
    for (int e = 0; e < 2; ++e) {
        int ex = e ? hi : lo;
        const float* w1 = w1base + ex * 64 * 128;   // [d][f]
        const float* w2 = w2base + ex * 128 * 64;   // [f][g]
        for (int i = tid; i < 8192; i += 768)
            w1t[e][i & 127][i >> 7] = f2bf(w1[i]);
        for (int i = tid; i < 8192; i += 768)
            w2t[e][i & 63][i >> 6] = f2bf(w2[i]);
    }
    __syncthreads();

    const int lane = tid & 63, w = tid >> 6, quad = lane >> 4, m16 = lane & 15;
    const int wid = chunk * 12 + w;
    const int WRK = nch * 12;
    const int nsub = (n + 31) >> 5;

    for (int s = wid; s < nsub; s += WRK) {
        const int base = s * 32;
        unsigned int gtok = 0, obase = 0; float wlo_ = 0.f, whi_ = 0.f;
        int posv = 0, valid = 0;
        if (lane < 32) {
            int j = base + lane;
            valid = (j < n);
            int jc = valid ? j : (n - 1);
            gtok = il[jc];
            float2 wv = wl[jc];
            wlo_ = valid ? wv.x : 0.f; whi_ = valid ? wv.y : 0.f;
            unsigned int b_ = gtok >> 14, h_ = gtok & 15, t_ = (gtok >> 4) & 1023;
            obase = ((b_ * 16 + h_) * 1024 + t_) * 64;
            posv = pos_ids[b_ * 1024 + t_];
        }

        bf16x8 Afr[2][2];
        #pragma unroll
        for (int mt2 = 0; mt2 < 2; ++mt2) {
            unsigned int gm = (unsigned int)__shfl((int)gtok, mt2 * 16 + m16, 64);
            const float* xr = x + (size_t)gm * 64 + 8 * quad;
            float4 xa0 = *(const float4*)(xr);
            float4 xa1 = *(const float4*)(xr + 4);
            float4 xb0 = *(const float4*)(xr + 32);
            float4 xb1 = *(const float4*)(xr + 36);
            bf16x8 A0, A1;
            A0[0] = (short)f2bf_f(xa0.x); A0[1] = (short)f2bf_f(xa0.y);
            A0[2] = (short)f2bf_f(xa0.z); A0[3] = (short)f2bf_f(xa0.w);
            A0[4] = (short)f2bf_f(xa1.x); A0[5] = (short)f2bf_f(xa1.y);
            A0[6] = (short)f2bf_f(xa1.z); A0[7] = (short)f2bf_f(xa1.w);
            A1[0] = (short)f2bf_f(xb0.x); A1[1] = (short)f2bf_f(xb0.y);
            A1[2] = (short)f2bf_f(xb0.z); A1[3] = (short)f2bf_f(xb0.w);
            A1[4] = (short)f2bf_f(xb1.x); A1[5] = (short)f2bf_f(xb1.y);
            A1[6] = (short)f2bf_f(xb1.z); A1[7] = (short)f2bf_f(xb1.w);
            Afr[mt2][0] = A0; Afr[mt2][1] = A1;
        }

        f32x4 acc2[2][2][4];   // [e][Mtile][nt]
        #pragma unroll
        for (int e = 0; e < 2; ++e)
            #pragma unroll
            for (int mt2 = 0; mt2 < 2; ++mt2)
                #pragma unroll
                for (int nt = 0; nt < 4; ++nt) acc2[e][mt2][nt] = (f32x4){0.f, 0.f, 0.f, 0.f};

        #pragma unroll
        for (int e = 0; e < 2; ++e) {
            #pragma unroll
            for (int kk = 0; kk < 4; ++kk) {
                int nt0 = 2 * kk, nt1 = 2 * kk + 1;
                bf16x8 b0a = *(const bf16x8*)&w1t[e][16 * nt0 + m16][8 * quad];
                bf16x8 b0b = *(const bf16x8*)&w1t[e][16 * nt0 + m16][32 + 8 * quad];
                bf16x8 b1a = *(const bf16x8*)&w1t[e][16 * nt1 + m16][8 * quad];
                bf16x8 b1b = *(const bf16x8*)&w1t[e][16 * nt1 + m16][32 + 8 * quad];
                #pragma unroll
                for (int mt2 = 0; mt2 < 2; ++mt2) {
                    f32x4 c0 = (f32x4){0.f, 0.f, 0.f, 0.f};
                    f32x4 c1 = (f32x4){0.f, 0.f, 0.f, 0.f};
                    c0 = __builtin_amdgcn_mfma_f32_16x16x32_bf16(Afr[mt2][0], b0a, c0, 0, 0, 0);
                    c0 = __builtin_amdgcn_mfma_f32_16x16x32_bf16(Afr[mt2][1], b0b, c0, 0, 0, 0);
                    c1 = __builtin_amdgcn_mfma_f32_16x16x32_bf16(Afr[mt2][0], b1a, c1, 0, 0, 0);
                    c1 = __builtin_amdgcn_mfma_f32_16x16x32_bf16(Afr[mt2][1], b1b, c1, 0, 0, 0);
                    #pragma unroll
                    for (int r = 0; r < 4; ++r) {
                        hsw[w][mt2 * 16 + 4 * quad + r][m16]      = f2bf_f(gelu_fast(c0[r]));
                        hsw[w][mt2 * 16 + 4 * quad + r][16 + m16] = f2bf_f(gelu_fast(c1[r]));
                    }
                }
                bf16x8 A2_0 = *(const bf16x8*)&hsw[w][m16][8 * quad];
                bf16x8 A2_1 = *(const bf16x8*)&hsw[w][16 + m16][8 * quad];
                #pragma unroll
                for (int nt2 = 0; nt2 < 4; ++nt2) {
                    bf16x8 b2 = *(const bf16x8*)&w2t[e][16 * nt2 + m16][32 * kk + 8 * quad];
                    acc2[e][0][nt2] = __builtin_amdgcn_mfma_f32_16x16x32_bf16(A2_0, b2, acc2[e][0][nt2], 0, 0, 0);
                    acc2[e][1][nt2] = __builtin_amdgcn_mfma_f32_16x16x32_bf16(A2_1, b2, acc2[e][1][nt2], 0, 0, 0);
                }
            }
        }

        #pragma unroll
        for (int mt2 = 0; mt2 < 2; ++mt2) {
            #pragma unroll
            for (int r = 0; r < 4; ++r) {
                int tk = mt2 * 16 + 4 * quad + r;
                float wlo_r = __shfl(wlo_, tk, 64);
                float whi_r = __shfl(whi_, tk, 64);
                int   pos_r = __shfl(posv, tk, 64);
                unsigned int ob = (unsigned int)__shfl((int)obase, tk, 64);
                int   val_r = __shfl(valid, tk, 64);
                if (p < 2) {
                    #pragma unroll
                    for (int ntp = 0; ntp < 2; ++ntp) {
                        int d = 16 * ntp + m16;
                        float v1 = wlo_r * acc2[0][mt2][ntp][r]     + whi_r * acc2[1][mt2][ntp][r];
                        float v2 = wlo_r * acc2[0][mt2][ntp + 2][r] + whi_r * acc2[1][mt2][ntp + 2][r];
                        float cd = cosb[pos_r * 64 + d];
                        float sd = sinb[pos_r * 64 + d];
                        if (val_r) {
                            outp[ob + d]      = f2bf(v1 * cd - v2 * sd);
                            outp[ob + d + 32] = f2bf(v2 * cd + v1 * sd);
                        }
                    }
                } else {
                    #pragma unroll
                    for (int nt = 0; nt < 4; ++nt) {
                        float v = wlo_r * acc2[0][mt2][nt][r] + whi_r * acc2[1][mt2][nt][r];
                        if (val_r) outp[ob + 16 * nt + m16] = f2bf(v);
                    }
                }
            }
        }
    }
}

// ============================================================================
// Kernel 3: fp32 -> bf16 convert (for o_w)
// ============================================================================
__global__ __launch_bounds__(256) void cvt_bf16_kernel(
    const float* __restrict__ in, u16* __restrict__ out, int n4)
{
    int i = blockIdx.x * 256 + threadIdx.x;
    if (i >= n4) return;
    float4 v = ((const float4*)in)[i];
    unsigned int lov = (unsigned int)f2bf(v.x) | ((unsigned int)f2bf(v.y) << 16);
    unsigned int hiv = (unsigned int)f2bf(v.z) | ((unsigned int)f2bf(v.w) << 16);
    ((uint2*)out)[i] = make_uint2(lov, hiv);
}

// ============================================================================
// Kernel 4: flash attention, bf16 MFMA (paired q-tiles (i, 15-i), grid 512,
// running-max softmax). R10: software-pipelined K/V staging — tile kt+1 is
// prefetched into registers while tile kt computes, hiding global latency.
// ============================================================================
__global__ __launch_bounds__(256) void attn_kernel(
    const u16* __restrict__ qbp, const u16* __restrict__ kbp,
    const u16* __restrict__ vbp, u16* __restrict__ ao)
{
    const int tid = threadIdx.x;
    const int i8 = blockIdx.x & 7;
    const int plane_i = blockIdx.x >> 3;           // 64 planes
    const int h = plane_i & 15, b = plane_i >> 4;
    const size_t plane = (size_t)plane_i * 1024 * 64;
    const u16* qp = qbp + plane;
    const u16* kp = kbp + plane;
    const u16* vp = vbp + plane;

    const int w = tid >> 6, lane = tid & 63, quad = lane >> 4, m16 = lane & 15;
    const int row = tid >> 2, seg = tid & 3;       // K staging coords
    const int kjv = tid & 63, dgv = tid >> 6;      // V staging coords

    __shared__ u16 Ks[64][72];
    __shared__ u16 Vt[64][72];        // [d][kj]
    __shared__ u16 Ps[4][16][72];     // per-wave P scratch

    #pragma unroll 1
    for (int half = 0; half < 2; ++half) {
        const int qt = half ? (15 - i8) : i8;
        const int q0 = qt * 64;

        const u16* qrow = &qp[(size_t)(q0 + 16 * w + m16) * 64 + 8 * quad];
        bf16x8 aq0 = *(const bf16x8*)(qrow);
        bf16x8 aq1 = *(const bf16x8*)(qrow + 32);

        // preload tile 0 into registers
        uint4 kr0, kr1; ushort4 vr0, vr1, vr2, vr3;
        {
            const uint4* src = (const uint4*)&kp[(size_t)row * 64 + seg * 16];
            kr0 = src[0]; kr1 = src[1];
            const u16* vb2 = &vp[(size_t)kjv * 64 + dgv * 4];
            vr0 = *(const ushort4*)(vb2);
            vr1 = *(const ushort4*)(vb2 + 16);
            vr2 = *(const ushort4*)(vb2 + 32);
            vr3 = *(const ushort4*)(vb2 + 48);
        }

        float m_r[4], l_r[4];
        #pragma unroll
        for (int i = 0; i < 4; ++i) { m_r[i] = -1e30f; l_r[i] = 0.f; }
        f32x4 oacc[4];
        #pragma unroll
        for (int i = 0; i < 4; ++i) oacc[i] = (f32x4){0.f, 0.f, 0.f, 0.f};

        for (int kt = 0; kt <= qt; ++kt) {
            __syncthreads();
            {   // commit prefetched tile to LDS
                uint4* dst = (uint4*)&Ks[row][seg * 16];
                dst[0] = kr0; dst[1] = kr1;
                int d0 = dgv * 4;
                Vt[d0 + 0][kjv] = vr0.x; Vt[d0 + 1][kjv] = vr0.y;
                Vt[d0 + 2][kjv] = vr0.z; Vt[d0 + 3][kjv] = vr0.w;
                Vt[d0 + 16][kjv] = vr1.x; Vt[d0 + 17][kjv] = vr1.y;
                Vt[d0 + 18][kjv] = vr1.z; Vt[d0 + 19][kjv] = vr1.w;
                Vt[d0 + 32][kjv] = vr2.x; Vt[d0 + 33][kjv] = vr2.y;
                Vt[d0 + 34][kjv] = vr2.z; Vt[d0 + 35][kjv] = vr2.w;
                Vt[d0 + 48][kjv] = vr3.x; Vt[d0 + 49][kjv] = vr3.y;
                Vt[d0 + 50][kjv] = vr3.z; Vt[d0 + 51][kjv] = vr3.w;
            }
            __syncthreads();
            if (kt < qt) {   // prefetch next tile (overlaps with compute below)
                const int k0n = (kt + 1) * 64;
                const uint4* src = (const uint4*)&kp[(size_t)(k0n + row) * 64 + seg * 16];
                kr0 = src[0]; kr1 = src[1];
                const u16* vb2 = &vp[(size_t)(k0n + kjv) * 64 + dgv * 4];
                vr0 = *(const ushort4*)(vb2);
                vr1 = *(const ushort4*)(vb2 + 16);
                vr2 = *(const ushort4*)(vb2 + 32);
                vr3 = *(const ushort4*)(vb2 + 48);
            }

            f32x4 sv[4];
            #pragma unroll
            for (int ct = 0; ct < 4; ++ct) {
                bf16x8 bk0 = *(const bf16x8*)&Ks[16 * ct + m16][8 * quad];
                bf16x8 bk1 = *(const bf16x8*)&Ks[16 * ct + m16][32 + 8 * quad];
                f32x4 acc = (f32x4){0.f, 0.f, 0.f, 0.f};
                acc = __builtin_amdgcn_mfma_f32_16x16x32_bf16(aq0, bk0, acc, 0, 0, 0);
                acc = __builtin_amdgcn_mfma_f32_16x16x32_bf16(aq1, bk1, acc, 0, 0, 0);
                sv[ct] = acc;
            }

            float s[4][4];
            const bool diag = (kt == qt);
            #pragma unroll
            for (int ct = 0; ct < 4; ++ct)
                #pragma unroll
                for (int reg = 0; reg < 4; ++reg) {
                    float v = sv[ct][reg] * 0.125f;
                    if (diag) {
                        int col = 16 * ct + m16;
                        int rw = 16 * w + 4 * quad + reg;
                        if (col > rw) v = -1e30f;
                    }
                    s[ct][reg] = v;
                }

            float nm[4], al[4];
            #pragma unroll
            for (int reg = 0; reg < 4; ++reg) {
                float rm = fmaxf(fmaxf(s[0][reg], s[1][reg]), fmaxf(s[2][reg], s[3][reg]));
                #pragma unroll
                for (int off = 1; off < 16; off <<= 1) rm = fmaxf(rm, __shfl_xor(rm, off, 16));
                float mn = fmaxf(m_r[reg], rm);
                nm[reg] = mn;
                al[reg] = __expf(m_r[reg] - mn);
            }
            #pragma unroll
            for (int reg = 0; reg < 4; ++reg) {
                float sum = 0.f;
                #pragma unroll
                for (int ct = 0; ct < 4; ++ct) {
                    float pv = __expf(s[ct][reg] - nm[reg]);
                    s[ct][reg] = pv;
                    sum += pv;
                }
                #pragma unroll
                for (int off = 1; off < 16; off <<= 1) sum += __shfl_xor(sum, off, 16);
                l_r[reg] = l_r[reg] * al[reg] + sum;
                m_r[reg] = nm[reg];
            }

            #pragma unroll
            for (int ct = 0; ct < 4; ++ct)
                #pragma unroll
                for (int reg = 0; reg < 4; ++reg)
                    Ps[w][4 * quad + reg][16 * ct + m16] = f2bf(s[ct][reg]);

            #pragma unroll
            for (int dt = 0; dt < 4; ++dt)
                #pragma unroll
                for (int reg = 0; reg < 4; ++reg) oacc[dt][reg] *= al[reg];

            bf16x8 ap0 = *(const bf16x8*)&Ps[w][m16][8 * quad];
            bf16x8 ap1 = *(const bf16x8*)&Ps[w][m16][32 + 8 * quad];
            #pragma unroll
            for (int dt = 0; dt < 4; ++dt) {
                bf16x8 bv0 = *(const bf16x8*)&Vt[16 * dt + m16][8 * quad];
                bf16x8 bv1 = *(const bf16x8*)&Vt[16 * dt + m16][32 + 8 * quad];
                oacc[dt] = __builtin_amdgcn_mfma_f32_16x16x32_bf16(ap0, bv0, oacc[dt], 0, 0, 0);
                oacc[dt] = __builtin_amdgcn_mfma_f32_16x16x32_bf16(ap1, bv1, oacc[dt], 0, 0, 0);
            }
        }

        #pragma unroll
        for (int reg = 0; reg < 4; ++reg) {
            float linv = 1.f / l_r[reg];
            int rw = q0 + 16 * w + 4 * quad + reg;
            size_t base = ((size_t)(b * 1024) + rw) * 1024 + h * 64;
            #pragma unroll
            for (int dt = 0; dt < 4; ++dt)
                ao[base + 16 * dt + m16] = f2bf(oacc[dt][reg] * linv);
        }
    }
}

// ============================================================================
// Kernel 5: output projection, bf16 MFMA gemm_bt. 128x128 tile, BK=32.
// ============================================================================
__global__ __launch_bounds__(256) void oproj_kernel(
    const u16* __restrict__ A, const u16* __restrict__ Bw,
    float* __restrict__ out)
{
    const int tid = threadIdx.x;
    const int bn = blockIdx.x & 7;
    const int bm = blockIdx.x >> 3;
    const int m0 = bm * 128, n0 = bn * 128;
    const int w = tid >> 6, lane = tid & 63, quad = lane >> 4, m16 = lane & 15;
    const int wm = (w >> 1) * 64, wn = (w & 1) * 64;

    __shared__ u16 As[128][32];
    __shared__ u16 Bs[128][32];

    f32x4 acc[4][4];
    #pragma unroll
    for (int mt = 0; mt < 4; ++mt)
        #pragma unroll
        for (int nt = 0; nt < 4; ++nt) acc[mt][nt] = (f32x4){0.f, 0.f, 0.f, 0.f};

    for (int k0 = 0; k0 < 1024; k0 += 32) {
        __syncthreads();
        {
            int rw = tid >> 1, sg = (tid & 1) * 16;
            const uint4* srcA = (const uint4*)&A[(size_t)(m0 + rw) * 1024 + k0 + sg];
            uint4 a0 = srcA[0], a1 = srcA[1];
            uint4* dstA = (uint4*)&As[rw][sg];
            dstA[0] = a0; dstA[1] = a1;
            const uint4* srcB = (const uint4*)&Bw[(size_t)(n0 + rw) * 1024 + k0 + sg];
            uint4 b0 = srcB[0], b1 = srcB[1];
            uint4* dstB = (uint4*)&Bs[rw][sg];
            dstB[0] = b0; dstB[1] = b1;
        }
        __syncthreads();
        bf16x8 af[4], bf_[4];
        #pragma unroll
        for (int mt = 0; mt < 4; ++mt) af[mt] = *(const bf16x8*)&As[wm + 16 * mt + m16][8 * quad];
        #pragma unroll
        for (int nt = 0; nt < 4; ++nt) bf_[nt] = *(const bf16x8*)&Bs[wn + 16 * nt + m16][8 * quad];
        #pragma unroll
        for (int mt = 0; mt < 4; ++mt)
            #pragma unroll
            for (int nt = 0; nt < 4; ++nt)
                acc[mt][nt] = __builtin_amdgcn_mfma_f32_16x16x32_bf16(af[mt], bf_[nt], acc[mt][nt], 0, 0, 0);
    }
    #pragma unroll
    for (int mt = 0; mt < 4; ++mt)
        #pragma unroll
        for (int nt = 0; nt < 4; ++nt)
            #pragma unroll
            for (int reg = 0; reg < 4; ++reg)
                out[(size_t)(m0 + wm + 16 * mt + 4 * quad + reg) * 1024 + n0 + wn + 16 * nt + m16] =
                    acc[mt][nt][reg];
}

// ============================================================================
extern "C" void kernel_launch(void* const* d_in, const int* in_sizes, int n_in,
                              void* d_out, int out_size, void* d_ws, size_t ws_size,
                              hipStream_t stream) {
    (void)in_sizes; (void)n_in; (void)out_size; (void)ws_size;
    const float* x    = (const float*)d_in[0];
    const int*   pid  = (const int*)  d_in[1];
    const float* cosb = (const float*)d_in[2];
    const float* sinb = (const float*)d_in[3];
    const float* rq   = (const float*)d_in[4];
    const float* rk   = (const float*)d_in[5];
    const float* rv   = (const float*)d_in[6];
    const float* qw1  = (const float*)d_in[7];
    const float* qw2  = (const float*)d_in[8];
    const float* kw1  = (const float*)d_in[9];
    const float* kw2  = (const float*)d_in[10];
    const float* vw1  = (const float*)d_in[11];
    const float* vw2  = (const float*)d_in[12];
    const float* ow   = (const float*)d_in[13];
    float* out = (float*)d_out;

    const size_t MB = 1u << 20;
    char* wsb = (char*)d_ws;
    u16* qb   = (u16*)(wsb + 0 * MB);      // 8 MB  bf16 [B,H,T,D]
    u16* kb   = (u16*)(wsb + 8 * MB);      // 8 MB
    u16* vb   = (u16*)(wsb + 16 * MB);     // 8 MB
    u16* aobf = (u16*)(wsb + 24 * MB);     // 8 MB  bf16 [B,T,C]
    u16* owbf = (u16*)(wsb + 32 * MB);     // 2 MB  bf16 o_w
    unsigned int* idxbuf = (unsigned int*)(wsb + 34 * MB);       // 6 MB
    float2*       wtbuf  = (float2*)(wsb + 41 * MB);             // 12 MB
    unsigned int* counts = (unsigned int*)(wsb + 54 * MB);       // 768 B
    unsigned int* blockinfo = (unsigned int*)(wsb + 54 * MB + 4096); // 1 KB

    hipMemsetAsync(counts, 0, 1024, stream);

    hipLaunchKernelGGL(router_kernel, dim3(256), dim3(256), 0, stream,
                       x, rq, rk, rv, counts, idxbuf, wtbuf);
    hipLaunchKernelGGL(sched_kernel, dim3(1), dim3(128), 0, stream,
                       counts, blockinfo);
    hipLaunchKernelGGL(cvt_bf16_kernel, dim3(1024), dim3(256), 0, stream,
                       ow, owbf, 1024 * 1024 / 4);
    hipLaunchKernelGGL(expert_kernel, dim3(GEXP), dim3(768), 0, stream,
                       x, pid, cosb, sinb, qw1, qw2, kw1, kw2, vw1, vw2,
                       counts, idxbuf, wtbuf, blockinfo, qb, kb, vb);
    hipLaunchKernelGGL(attn_kernel, dim3(512), dim3(256), 0, stream,
                       qb, kb, vb, aobf);
    hipLaunchKernelGGL(oproj_kernel, dim3(256), dim3(256), 0, stream,
                       aobf, owbf, out);
}